// Round 1
// baseline (1385.595 us; speedup 1.0000x reference)
//
#include <hip/hip_runtime.h>
#include <math.h>

// Problem constants (from reference)
#define N_NODES 40000
#define N_EDGES 640000
#define F_IN    1280
#define H       128
#define NG      64
#define OUTD    273
#define FC1D    1024
#define NEG_SLOPE 0.2f
#define BN_EPS  1e-5f

// ---------------------------------------------------------------------------
// CSR build: histogram -> exclusive scan -> fill
// ---------------------------------------------------------------------------
__global__ void edge_hist(const int* __restrict__ dst, int* __restrict__ cnt, int e) {
    int i = blockIdx.x * blockDim.x + threadIdx.x;
    if (i < e) atomicAdd(&cnt[dst[i]], 1);
}

// single block, 1024 threads; each thread serially scans a 40-element chunk,
// then one Hillis-Steele block scan over the 1024 chunk totals.
__global__ void scan_excl(const int* __restrict__ cnt, int* __restrict__ row_ptr, int n) {
    const int CH = 40;                      // 1024*40 = 40960 >= 40000
    __shared__ int sm[1024];
    int tid = threadIdx.x;
    int start = tid * CH;
    int local[CH];
    int s = 0;
    #pragma unroll
    for (int k = 0; k < CH; ++k) {
        int i = start + k;
        int v = (i < n) ? cnt[i] : 0;
        local[k] = s;
        s += v;
    }
    sm[tid] = s;
    __syncthreads();
    for (int off = 1; off < 1024; off <<= 1) {
        int t = (tid >= off) ? sm[tid - off] : 0;
        __syncthreads();
        sm[tid] += t;
        __syncthreads();
    }
    int base = sm[tid] - s;                 // exclusive prefix of chunk totals
    #pragma unroll
    for (int k = 0; k < CH; ++k) {
        int i = start + k;
        if (i < n) row_ptr[i] = base + local[k];
    }
    if (tid == 1023) row_ptr[n] = sm[1023];
}

__global__ void edge_fill(const int* __restrict__ src, const int* __restrict__ dst,
                          const int* __restrict__ row_ptr, int* __restrict__ fill,
                          int* __restrict__ csr_src, int e) {
    int i = blockIdx.x * blockDim.x + threadIdx.x;
    if (i < e) {
        int d = dst[i];
        int pos = row_ptr[d] + atomicAdd(&fill[d], 1);
        csr_src[pos] = src[i];
    }
}

// ---------------------------------------------------------------------------
// fp32 tiled GEMM: C[M,128] = A[M,K] @ B[K,128].  BM=128, BK=32, 8x8 microtile.
// ---------------------------------------------------------------------------
#define BM 128
#define BKK 32

__global__ __launch_bounds__(256) void gemm_f32(const float* __restrict__ A,
                                                const float* __restrict__ B,
                                                float* __restrict__ C,
                                                int M, int K) {
    __shared__ float As[BM][BKK + 1];     // +1 pad
    __shared__ float Bs[BKK][H + 4];
    int tid = threadIdx.x;
    int tx = tid & 15, ty = tid >> 4;
    int m0 = blockIdx.x * BM;
    float acc[8][8] = {};
    for (int k0 = 0; k0 < K; k0 += BKK) {
        // A tile: 128 rows x 32 cols = 1024 float4
        #pragma unroll
        for (int q = 0; q < 4; ++q) {
            int idx = tid + q * 256;
            int row = idx >> 3;
            int c4 = idx & 7;
            float4 v = make_float4(0.f, 0.f, 0.f, 0.f);
            if (m0 + row < M)
                v = *(const float4*)(A + (size_t)(m0 + row) * K + k0 + c4 * 4);
            As[row][c4 * 4 + 0] = v.x; As[row][c4 * 4 + 1] = v.y;
            As[row][c4 * 4 + 2] = v.z; As[row][c4 * 4 + 3] = v.w;
        }
        // B tile: 32 rows x 128 cols = 1024 float4
        #pragma unroll
        for (int q = 0; q < 4; ++q) {
            int idx = tid + q * 256;
            int row = idx >> 5;
            int c4 = idx & 31;
            float4 v = *(const float4*)(B + (size_t)(k0 + row) * H + c4 * 4);
            Bs[row][c4 * 4 + 0] = v.x; Bs[row][c4 * 4 + 1] = v.y;
            Bs[row][c4 * 4 + 2] = v.z; Bs[row][c4 * 4 + 3] = v.w;
        }
        __syncthreads();
        #pragma unroll
        for (int kk = 0; kk < BKK; ++kk) {
            float a[8], b[8];
            #pragma unroll
            for (int i = 0; i < 8; ++i) a[i] = As[ty * 8 + i][kk];
            #pragma unroll
            for (int j = 0; j < 8; ++j) b[j] = Bs[kk][tx * 8 + j];
            #pragma unroll
            for (int i = 0; i < 8; ++i)
                #pragma unroll
                for (int j = 0; j < 8; ++j) acc[i][j] += a[i] * b[j];
        }
        __syncthreads();
    }
    #pragma unroll
    for (int i = 0; i < 8; ++i) {
        int row = m0 + ty * 8 + i;
        if (row < M) {
            #pragma unroll
            for (int j = 0; j < 8; j += 4) {
                float4 v = make_float4(acc[i][j], acc[i][j + 1], acc[i][j + 2], acc[i][j + 3]);
                *(float4*)(C + (size_t)row * H + tx * 8 + j) = v;
            }
        }
    }
}

// ---------------------------------------------------------------------------
// per-node attention scores: hs = h.a_src, hd = h.a_dst   (one wave per node)
// ---------------------------------------------------------------------------
__global__ void scores_k(const float* __restrict__ h, const float* __restrict__ a_s,
                         const float* __restrict__ a_d, float* __restrict__ hs,
                         float* __restrict__ hd, int n) {
    int wv = (blockIdx.x * blockDim.x + threadIdx.x) >> 6;
    int lane = threadIdx.x & 63;
    if (wv >= n) return;
    float v0 = h[(size_t)wv * H + lane];
    float v1 = h[(size_t)wv * H + 64 + lane];
    float s = v0 * a_s[lane] + v1 * a_s[64 + lane];
    float d = v0 * a_d[lane] + v1 * a_d[64 + lane];
    #pragma unroll
    for (int off = 32; off; off >>= 1) {
        s += __shfl_xor(s, off);
        d += __shfl_xor(d, off);
    }
    if (lane == 0) { hs[wv] = s; hd[wv] = d; }
}

// ---------------------------------------------------------------------------
// fused segment softmax + weighted aggregation, one wave per dst node
// ---------------------------------------------------------------------------
__global__ void attn_agg(const float* __restrict__ h, const float* __restrict__ hs,
                         const float* __restrict__ hd, const int* __restrict__ row_ptr,
                         const int* __restrict__ csr_src, const float* __restrict__ bias,
                         float* __restrict__ out, int n, int relu_flag) {
    int wv = (blockIdx.x * blockDim.x + threadIdx.x) >> 6;
    int lane = threadIdx.x & 63;
    if (wv >= n) return;
    int p0 = row_ptr[wv], p1 = row_ptr[wv + 1];
    float hdi = hd[wv];

    // pass 1: segment max
    float m = -3.4e38f;
    for (int p = p0 + lane; p < p1; p += 64) {
        float e = hs[csr_src[p]] + hdi;
        e = (e >= 0.f) ? e : NEG_SLOPE * e;
        m = fmaxf(m, e);
    }
    #pragma unroll
    for (int off = 32; off; off >>= 1) m = fmaxf(m, __shfl_xor(m, off));

    // pass 2: denom
    float dsum = 0.f;
    for (int p = p0 + lane; p < p1; p += 64) {
        float e = hs[csr_src[p]] + hdi;
        e = (e >= 0.f) ? e : NEG_SLOPE * e;
        dsum += __expf(e - m);
    }
    #pragma unroll
    for (int off = 32; off; off >>= 1) dsum += __shfl_xor(dsum, off);
    float inv = 1.f / (dsum + 1e-16f);

    // pass 3: aggregate  (features: lane, lane+64)
    float acc0 = 0.f, acc1 = 0.f;
    #pragma unroll 2
    for (int p = p0; p < p1; ++p) {
        int s = csr_src[p];                       // wave-uniform
        float e = hs[s] + hdi;
        e = (e >= 0.f) ? e : NEG_SLOPE * e;
        float alpha = __expf(e - m) * inv;
        acc0 += alpha * h[(size_t)s * H + lane];
        acc1 += alpha * h[(size_t)s * H + 64 + lane];
    }
    float o0 = acc0 + bias[lane];
    float o1 = acc1 + bias[64 + lane];
    if (relu_flag) { o0 = fmaxf(o0, 0.f); o1 = fmaxf(o1, 0.f); }
    out[(size_t)wv * H + lane] = o0;
    out[(size_t)wv * H + 64 + lane] = o1;
}

// ---------------------------------------------------------------------------
// global mean pool per graph (batch is sorted -> binary search boundaries)
// ---------------------------------------------------------------------------
__global__ void pool_k(const float* __restrict__ h, const int* __restrict__ batch,
                       float* __restrict__ pooled, int n) {
    int g = blockIdx.x;       // 64 blocks
    int f = threadIdx.x;      // 128 threads
    int lo = 0, hi = n;
    while (lo < hi) { int mid = (lo + hi) >> 1; if (batch[mid] < g) lo = mid + 1; else hi = mid; }
    int start = lo;
    lo = start; hi = n;
    while (lo < hi) { int mid = (lo + hi) >> 1; if (batch[mid] < g + 1) lo = mid + 1; else hi = mid; }
    int end = lo;
    float acc = 0.f;
    for (int i = start; i < end; ++i) acc += h[(size_t)i * H + f];
    float cnt = (float)(end - start);
    pooled[g * H + f] = acc / fmaxf(cnt, 1.f);
}

// ---------------------------------------------------------------------------
// FC1 + BN(eval) + ReLU : z[64][1024]
// ---------------------------------------------------------------------------
__global__ void fc1_bn_relu(const float* __restrict__ pooled, const float* __restrict__ W,
                            const float* __restrict__ b, const float* __restrict__ bng,
                            const float* __restrict__ bnb, const float* __restrict__ bnrm,
                            const float* __restrict__ bnrv, float* __restrict__ z) {
    int g = blockIdx.x >> 2;
    int j = ((blockIdx.x & 3) << 8) + threadIdx.x;     // 0..1023
    const float* pr = pooled + g * H;
    float acc = b[j];
    #pragma unroll 8
    for (int k = 0; k < H; ++k) acc += pr[k] * W[k * FC1D + j];
    float v = (acc - bnrm[j]) * rsqrtf(bnrv[j] + BN_EPS) * bng[j] + bnb[j];
    z[g * FC1D + j] = fmaxf(v, 0.f);
}

// ---------------------------------------------------------------------------
// FC2 + sigmoid : out[64][273]
// ---------------------------------------------------------------------------
__global__ void fc2_sig(const float* __restrict__ z, const float* __restrict__ W,
                        const float* __restrict__ b, float* __restrict__ out) {
    int g = blockIdx.x;
    int j = threadIdx.x;
    if (j >= OUTD) return;
    const float* zr = z + g * FC1D;
    float acc = b[j];
    #pragma unroll 4
    for (int k = 0; k < FC1D; ++k) acc += zr[k] * W[k * OUTD + j];
    out[g * OUTD + j] = 1.f / (1.f + __expf(-acc));
}

// ---------------------------------------------------------------------------
extern "C" void kernel_launch(void* const* d_in, const int* in_sizes, int n_in,
                              void* d_out, int out_size, void* d_ws, size_t ws_size,
                              hipStream_t stream) {
    const float* x     = (const float*)d_in[0];
    const int*   eidx  = (const int*)d_in[1];
    const int*   batch = (const int*)d_in[2];
    const float* W1 = (const float*)d_in[3];  const float* b1 = (const float*)d_in[4];
    const float* as1 = (const float*)d_in[5]; const float* ad1 = (const float*)d_in[6];
    const float* W2 = (const float*)d_in[7];  const float* b2 = (const float*)d_in[8];
    const float* as2 = (const float*)d_in[9]; const float* ad2 = (const float*)d_in[10];
    const float* W3 = (const float*)d_in[11]; const float* b3 = (const float*)d_in[12];
    const float* as3 = (const float*)d_in[13]; const float* ad3 = (const float*)d_in[14];
    const float* fc1W = (const float*)d_in[15]; const float* fc1b = (const float*)d_in[16];
    const float* bng = (const float*)d_in[17];  const float* bnb = (const float*)d_in[18];
    const float* bnrm = (const float*)d_in[19]; const float* bnrv = (const float*)d_in[20];
    const float* fc2W = (const float*)d_in[21]; const float* fc2b = (const float*)d_in[22];
    const int* src = eidx;
    const int* dst = eidx + N_EDGES;

    // workspace layout
    float* hW      = (float*)d_ws;                     // N*H
    float* hA      = hW + (size_t)N_NODES * H;         // N*H
    float* hs      = hA + (size_t)N_NODES * H;         // N
    float* hd      = hs + N_NODES;                     // N
    int*   row_ptr = (int*)(hd + N_NODES);             // N+1
    int*   row_cnt = row_ptr + (N_NODES + 1);          // N
    int*   csr_src = row_cnt + N_NODES;                // E
    float* pooled  = (float*)(csr_src + N_EDGES);      // G*H
    float* z       = pooled + NG * H;                  // G*1024

    const int EB = (N_EDGES + 255) / 256;
    const int NW = (N_NODES * 64 + 255) / 256;         // one wave per node

    // ---- CSR build (by dst) ----
    hipMemsetAsync(row_cnt, 0, N_NODES * sizeof(int), stream);
    edge_hist<<<EB, 256, 0, stream>>>(dst, row_cnt, N_EDGES);
    scan_excl<<<1, 1024, 0, stream>>>(row_cnt, row_ptr, N_NODES);
    hipMemsetAsync(row_cnt, 0, N_NODES * sizeof(int), stream);
    edge_fill<<<EB, 256, 0, stream>>>(src, dst, row_ptr, row_cnt, csr_src, N_EDGES);

    const int GB = (N_NODES + BM - 1) / BM;            // 313

    // ---- layer 1 ----
    gemm_f32<<<GB, 256, 0, stream>>>(x, W1, hW, N_NODES, F_IN);
    scores_k<<<NW, 256, 0, stream>>>(hW, as1, ad1, hs, hd, N_NODES);
    attn_agg<<<NW, 256, 0, stream>>>(hW, hs, hd, row_ptr, csr_src, b1, hA, N_NODES, 1);
    // ---- layer 2 ----
    gemm_f32<<<GB, 256, 0, stream>>>(hA, W2, hW, N_NODES, H);
    scores_k<<<NW, 256, 0, stream>>>(hW, as2, ad2, hs, hd, N_NODES);
    attn_agg<<<NW, 256, 0, stream>>>(hW, hs, hd, row_ptr, csr_src, b2, hA, N_NODES, 1);
    // ---- layer 3 (no relu) ----
    gemm_f32<<<GB, 256, 0, stream>>>(hA, W3, hW, N_NODES, H);
    scores_k<<<NW, 256, 0, stream>>>(hW, as3, ad3, hs, hd, N_NODES);
    attn_agg<<<NW, 256, 0, stream>>>(hW, hs, hd, row_ptr, csr_src, b3, hA, N_NODES, 0);

    // ---- head ----
    pool_k<<<NG, H, 0, stream>>>(hA, batch, pooled, N_NODES);
    fc1_bn_relu<<<NG * 4, 256, 0, stream>>>(pooled, fc1W, fc1b, bng, bnb, bnrm, bnrv, z);
    fc2_sig<<<NG, 320, 0, stream>>>(z, fc2W, fc2b, (float*)d_out);
}

// Round 2
// 1049.789 us; speedup vs baseline: 1.3199x; 1.3199x over previous
//
#include <hip/hip_runtime.h>
#include <math.h>

// Problem constants (from reference)
#define N_NODES 40000
#define N_EDGES 640000
#define F_IN    1280
#define H       128
#define NG      64
#define OUTD    273
#define FC1D    1024
#define NEG_SLOPE 0.2f
#define BN_EPS  1e-5f

typedef __attribute__((ext_vector_type(8))) short short8;
typedef __attribute__((ext_vector_type(4))) float f32x4;

// fp32 -> bf16 (RNE) and back, as bit patterns
__device__ __forceinline__ unsigned short f2bf(float f) {
    unsigned u = __float_as_uint(f);
    u += 0x7FFF + ((u >> 16) & 1);
    return (unsigned short)(u >> 16);
}
__device__ __forceinline__ float bf2f(unsigned short s) {
    return __uint_as_float((unsigned)s << 16);
}

// ---------------------------------------------------------------------------
// CSR build: histogram -> exclusive scan -> fill
// ---------------------------------------------------------------------------
__global__ void edge_hist(const int* __restrict__ dst, int* __restrict__ cnt, int e) {
    int i = blockIdx.x * blockDim.x + threadIdx.x;
    if (i < e) atomicAdd(&cnt[dst[i]], 1);
}

__global__ void scan_excl(const int* __restrict__ cnt, int* __restrict__ row_ptr, int n) {
    const int CH = 40;                      // 1024*40 = 40960 >= 40000
    __shared__ int sm[1024];
    int tid = threadIdx.x;
    int start = tid * CH;
    int local[CH];
    int s = 0;
    #pragma unroll
    for (int k = 0; k < CH; ++k) {
        int i = start + k;
        int v = (i < n) ? cnt[i] : 0;
        local[k] = s;
        s += v;
    }
    sm[tid] = s;
    __syncthreads();
    for (int off = 1; off < 1024; off <<= 1) {
        int t = (tid >= off) ? sm[tid - off] : 0;
        __syncthreads();
        sm[tid] += t;
        __syncthreads();
    }
    int base = sm[tid] - s;
    #pragma unroll
    for (int k = 0; k < CH; ++k) {
        int i = start + k;
        if (i < n) row_ptr[i] = base + local[k];
    }
    if (tid == 1023) row_ptr[n] = sm[1023];
}

__global__ void edge_fill(const int* __restrict__ src, const int* __restrict__ dst,
                          const int* __restrict__ row_ptr, int* __restrict__ fill,
                          int* __restrict__ csr_src, int e) {
    int i = blockIdx.x * blockDim.x + threadIdx.x;
    if (i < e) {
        int d = dst[i];
        int pos = row_ptr[d] + atomicAdd(&fill[d], 1);
        csr_src[pos] = src[i];
    }
}

// ---------------------------------------------------------------------------
// weight prep: W[K][128] fp32  ->  Wt_hi[128][K], Wt_lo[128][K] (bf16 split)
// ---------------------------------------------------------------------------
__global__ void wprep(const float* __restrict__ W, unsigned short* __restrict__ Wth,
                      unsigned short* __restrict__ Wtl, int K) {
    int i = blockIdx.x * blockDim.x + threadIdx.x;
    if (i >= K * H) return;
    int k = i >> 7, n = i & 127;
    float v = W[i];
    unsigned short h = f2bf(v);
    float r = v - bf2f(h);
    Wth[(size_t)n * K + k] = h;
    Wtl[(size_t)n * K + k] = f2bf(r);
}

// ---------------------------------------------------------------------------
// GEMM via bf16x3 MFMA: C[M,128] = A[M,K] @ B[K,128], fp32-equivalent accuracy.
// A converted to (hi,lo) bf16 in staging; B pre-split as Bt_hi/Bt_lo [128][K].
// BM=64, 256 threads (4 waves, 2x2), wave tile 32x64, frags 2(M) x 4(N) of
// 16x16x32. M must be a multiple of 64, K a multiple of 32.
// ---------------------------------------------------------------------------
__global__ __launch_bounds__(256) void gemm_bf16x3(
    const float* __restrict__ A, const unsigned short* __restrict__ Bth,
    const unsigned short* __restrict__ Btl, float* __restrict__ C, int K)
{
    __shared__ unsigned short Ah[64][32], Al[64][32];
    __shared__ unsigned short Bh[128][32], Bl[128][32];
    int tid = threadIdx.x;
    int lane = tid & 63, wv = tid >> 6;
    int wm = wv >> 1, wn = wv & 1;          // 2x2 wave grid
    int m0 = blockIdx.x * 64;

    f32x4 acc[2][4] = {};

    // staging assignments
    int arow = tid >> 2, akq = (tid & 3) * 8;          // A: 64 rows x (4 x 8 k)
    int bn = tid & 127, bsel = tid >> 7;               // B: 128 n-rows, hi/lo half
    const unsigned short* Bsrc = bsel ? Btl : Bth;

    int fr = lane & 15, kg = (lane >> 4) * 8;

    for (int k0 = 0; k0 < K; k0 += 32) {
        // ---- stage A tile (fp32 -> hi/lo bf16) ----
        const float* ap = A + (size_t)(m0 + arow) * K + k0 + akq;
        float4 v0 = *(const float4*)ap;
        float4 v1 = *(const float4*)(ap + 4);
        float f[8] = {v0.x, v0.y, v0.z, v0.w, v1.x, v1.y, v1.z, v1.w};
        short8 hv, lv;
        #pragma unroll
        for (int j = 0; j < 8; ++j) {
            unsigned short hh = f2bf(f[j]);
            hv[j] = (short)hh;
            lv[j] = (short)f2bf(f[j] - bf2f(hh));
        }
        *(short8*)&Ah[arow][akq] = hv;
        *(short8*)&Al[arow][akq] = lv;

        // ---- stage B tile (pre-split bf16, 64B per thread) ----
        const uint4* bp = (const uint4*)(Bsrc + (size_t)bn * K + k0);
        uint4 b0 = bp[0], b1 = bp[1], b2 = bp[2], b3 = bp[3];
        uint4* bd = (uint4*)(bsel ? &Bl[bn][0] : &Bh[bn][0]);
        bd[0] = b0; bd[1] = b1; bd[2] = b2; bd[3] = b3;

        __syncthreads();

        // ---- fragments + MFMA ----
        short8 ahf[2], alf[2], bhf[4], blf[4];
        #pragma unroll
        for (int m = 0; m < 2; ++m) {
            int r = wm * 32 + m * 16 + fr;
            ahf[m] = *(const short8*)&Ah[r][kg];
            alf[m] = *(const short8*)&Al[r][kg];
        }
        #pragma unroll
        for (int n = 0; n < 4; ++n) {
            int c = wn * 64 + n * 16 + fr;
            bhf[n] = *(const short8*)&Bh[c][kg];
            blf[n] = *(const short8*)&Bl[c][kg];
        }
        #pragma unroll
        for (int m = 0; m < 2; ++m)
            #pragma unroll
            for (int n = 0; n < 4; ++n) {
                acc[m][n] = __builtin_amdgcn_mfma_f32_16x16x32_bf16(ahf[m], bhf[n], acc[m][n], 0, 0, 0);
                acc[m][n] = __builtin_amdgcn_mfma_f32_16x16x32_bf16(ahf[m], blf[n], acc[m][n], 0, 0, 0);
                acc[m][n] = __builtin_amdgcn_mfma_f32_16x16x32_bf16(alf[m], bhf[n], acc[m][n], 0, 0, 0);
            }
        __syncthreads();
    }

    // ---- epilogue: C/D layout col=lane&15, row=(lane>>4)*4+i  [m89] ----
    int rq = (lane >> 4) * 4;
    #pragma unroll
    for (int m = 0; m < 2; ++m)
        #pragma unroll
        for (int n = 0; n < 4; ++n) {
            int col = wn * 64 + n * 16 + fr;
            #pragma unroll
            for (int i = 0; i < 4; ++i) {
                int row = m0 + wm * 32 + m * 16 + rq + i;
                C[(size_t)row * H + col] = acc[m][n][i];
            }
        }
}

// ---------------------------------------------------------------------------
// per-node attention scores: hs = h.a_src, hd = h.a_dst   (one wave per node)
// ---------------------------------------------------------------------------
__global__ void scores_k(const float* __restrict__ h, const float* __restrict__ a_s,
                         const float* __restrict__ a_d, float* __restrict__ hs,
                         float* __restrict__ hd, int n) {
    int wv = (blockIdx.x * blockDim.x + threadIdx.x) >> 6;
    int lane = threadIdx.x & 63;
    if (wv >= n) return;
    float v0 = h[(size_t)wv * H + lane];
    float v1 = h[(size_t)wv * H + 64 + lane];
    float s = v0 * a_s[lane] + v1 * a_s[64 + lane];
    float d = v0 * a_d[lane] + v1 * a_d[64 + lane];
    #pragma unroll
    for (int off = 32; off; off >>= 1) {
        s += __shfl_xor(s, off);
        d += __shfl_xor(d, off);
    }
    if (lane == 0) { hs[wv] = s; hd[wv] = d; }
}

// ---------------------------------------------------------------------------
// fused segment softmax + weighted aggregation, one wave per dst node
// ---------------------------------------------------------------------------
__global__ void attn_agg(const float* __restrict__ h, const float* __restrict__ hs,
                         const float* __restrict__ hd, const int* __restrict__ row_ptr,
                         const int* __restrict__ csr_src, const float* __restrict__ bias,
                         float* __restrict__ out, int n, int relu_flag) {
    int wv = (blockIdx.x * blockDim.x + threadIdx.x) >> 6;
    int lane = threadIdx.x & 63;
    if (wv >= n) return;
    int p0 = row_ptr[wv], p1 = row_ptr[wv + 1];
    float hdi = hd[wv];

    // pass 1: segment max
    float m = -3.4e38f;
    for (int p = p0 + lane; p < p1; p += 64) {
        float e = hs[csr_src[p]] + hdi;
        e = (e >= 0.f) ? e : NEG_SLOPE * e;
        m = fmaxf(m, e);
    }
    #pragma unroll
    for (int off = 32; off; off >>= 1) m = fmaxf(m, __shfl_xor(m, off));

    // pass 2: denom
    float dsum = 0.f;
    for (int p = p0 + lane; p < p1; p += 64) {
        float e = hs[csr_src[p]] + hdi;
        e = (e >= 0.f) ? e : NEG_SLOPE * e;
        dsum += __expf(e - m);
    }
    #pragma unroll
    for (int off = 32; off; off >>= 1) dsum += __shfl_xor(dsum, off);
    float inv = 1.f / (dsum + 1e-16f);

    // pass 3: aggregate  (features: lane, lane+64)
    float acc0 = 0.f, acc1 = 0.f;
    #pragma unroll 2
    for (int p = p0; p < p1; ++p) {
        int s = csr_src[p];                       // wave-uniform
        float e = hs[s] + hdi;
        e = (e >= 0.f) ? e : NEG_SLOPE * e;
        float alpha = __expf(e - m) * inv;
        acc0 += alpha * h[(size_t)s * H + lane];
        acc1 += alpha * h[(size_t)s * H + 64 + lane];
    }
    float o0 = acc0 + bias[lane];
    float o1 = acc1 + bias[64 + lane];
    if (relu_flag) { o0 = fmaxf(o0, 0.f); o1 = fmaxf(o1, 0.f); }
    out[(size_t)wv * H + lane] = o0;
    out[(size_t)wv * H + 64 + lane] = o1;
}

// ---------------------------------------------------------------------------
// global mean pool per graph (batch is sorted -> binary search boundaries)
// ---------------------------------------------------------------------------
__global__ void pool_k(const float* __restrict__ h, const int* __restrict__ batch,
                       float* __restrict__ pooled, int n) {
    int g = blockIdx.x;       // 64 blocks
    int f = threadIdx.x;      // 128 threads
    int lo = 0, hi = n;
    while (lo < hi) { int mid = (lo + hi) >> 1; if (batch[mid] < g) lo = mid + 1; else hi = mid; }
    int start = lo;
    lo = start; hi = n;
    while (lo < hi) { int mid = (lo + hi) >> 1; if (batch[mid] < g + 1) lo = mid + 1; else hi = mid; }
    int end = lo;
    float acc = 0.f;
    for (int i = start; i < end; ++i) acc += h[(size_t)i * H + f];
    float cnt = (float)(end - start);
    pooled[g * H + f] = acc / fmaxf(cnt, 1.f);
}

// ---------------------------------------------------------------------------
// FC1 + BN(eval) + ReLU : z[64][1024]
// ---------------------------------------------------------------------------
__global__ void fc1_bn_relu(const float* __restrict__ pooled, const float* __restrict__ W,
                            const float* __restrict__ b, const float* __restrict__ bng,
                            const float* __restrict__ bnb, const float* __restrict__ bnrm,
                            const float* __restrict__ bnrv, float* __restrict__ z) {
    int g = blockIdx.x >> 2;
    int j = ((blockIdx.x & 3) << 8) + threadIdx.x;     // 0..1023
    const float* pr = pooled + g * H;
    float acc = b[j];
    #pragma unroll 8
    for (int k = 0; k < H; ++k) acc += pr[k] * W[k * FC1D + j];
    float v = (acc - bnrm[j]) * rsqrtf(bnrv[j] + BN_EPS) * bng[j] + bnb[j];
    z[g * FC1D + j] = fmaxf(v, 0.f);
}

// ---------------------------------------------------------------------------
// FC2 + sigmoid : out[64][273]
// ---------------------------------------------------------------------------
__global__ void fc2_sig(const float* __restrict__ z, const float* __restrict__ W,
                        const float* __restrict__ b, float* __restrict__ out) {
    int g = blockIdx.x;
    int j = threadIdx.x;
    if (j >= OUTD) return;
    const float* zr = z + g * FC1D;
    float acc = b[j];
    #pragma unroll 4
    for (int k = 0; k < FC1D; ++k) acc += zr[k] * W[k * OUTD + j];
    out[g * OUTD + j] = 1.f / (1.f + __expf(-acc));
}

// ---------------------------------------------------------------------------
extern "C" void kernel_launch(void* const* d_in, const int* in_sizes, int n_in,
                              void* d_out, int out_size, void* d_ws, size_t ws_size,
                              hipStream_t stream) {
    const float* x     = (const float*)d_in[0];
    const int*   eidx  = (const int*)d_in[1];
    const int*   batch = (const int*)d_in[2];
    const float* W1 = (const float*)d_in[3];  const float* b1 = (const float*)d_in[4];
    const float* as1 = (const float*)d_in[5]; const float* ad1 = (const float*)d_in[6];
    const float* W2 = (const float*)d_in[7];  const float* b2 = (const float*)d_in[8];
    const float* as2 = (const float*)d_in[9]; const float* ad2 = (const float*)d_in[10];
    const float* W3 = (const float*)d_in[11]; const float* b3 = (const float*)d_in[12];
    const float* as3 = (const float*)d_in[13]; const float* ad3 = (const float*)d_in[14];
    const float* fc1W = (const float*)d_in[15]; const float* fc1b = (const float*)d_in[16];
    const float* bng = (const float*)d_in[17];  const float* bnb = (const float*)d_in[18];
    const float* bnrm = (const float*)d_in[19]; const float* bnrv = (const float*)d_in[20];
    const float* fc2W = (const float*)d_in[21]; const float* fc2b = (const float*)d_in[22];
    const int* src = eidx;
    const int* dst = eidx + N_EDGES;

    // workspace layout
    float* hW      = (float*)d_ws;                     // N*H
    float* hA      = hW + (size_t)N_NODES * H;         // N*H
    float* hs      = hA + (size_t)N_NODES * H;         // N
    float* hd      = hs + N_NODES;                     // N
    int*   row_ptr = (int*)(hd + N_NODES);             // N+1
    int*   row_cnt = row_ptr + (N_NODES + 1);          // N
    int*   csr_src = row_cnt + N_NODES;                // E
    float* pooled  = (float*)(csr_src + N_EDGES);      // G*H
    float* z       = pooled + NG * H;                  // G*1024
    unsigned short* wt1h = (unsigned short*)(z + NG * FC1D);   // 128*1280
    unsigned short* wt1l = wt1h + (size_t)H * F_IN;
    unsigned short* wt2h = wt1l + (size_t)H * F_IN;            // 128*128
    unsigned short* wt2l = wt2h + (size_t)H * H;
    unsigned short* wt3h = wt2l + (size_t)H * H;
    unsigned short* wt3l = wt3h + (size_t)H * H;

    const int EB = (N_EDGES + 255) / 256;
    const int NW = (N_NODES * 64 + 255) / 256;         // one wave per node
    const int GB = N_NODES / 64;                       // 625 gemm blocks

    // ---- weight split/transpose (tiny) ----
    wprep<<<(F_IN * H + 255) / 256, 256, 0, stream>>>(W1, wt1h, wt1l, F_IN);
    wprep<<<(H * H + 255) / 256, 256, 0, stream>>>(W2, wt2h, wt2l, H);
    wprep<<<(H * H + 255) / 256, 256, 0, stream>>>(W3, wt3h, wt3l, H);

    // ---- CSR build (by dst) ----
    hipMemsetAsync(row_cnt, 0, N_NODES * sizeof(int), stream);
    edge_hist<<<EB, 256, 0, stream>>>(dst, row_cnt, N_EDGES);
    scan_excl<<<1, 1024, 0, stream>>>(row_cnt, row_ptr, N_NODES);
    hipMemsetAsync(row_cnt, 0, N_NODES * sizeof(int), stream);
    edge_fill<<<EB, 256, 0, stream>>>(src, dst, row_ptr, row_cnt, csr_src, N_EDGES);

    // ---- layer 1 ----
    gemm_bf16x3<<<GB, 256, 0, stream>>>(x, wt1h, wt1l, hW, F_IN);
    scores_k<<<NW, 256, 0, stream>>>(hW, as1, ad1, hs, hd, N_NODES);
    attn_agg<<<NW, 256, 0, stream>>>(hW, hs, hd, row_ptr, csr_src, b1, hA, N_NODES, 1);
    // ---- layer 2 ----
    gemm_bf16x3<<<GB, 256, 0, stream>>>(hA, wt2h, wt2l, hW, H);
    scores_k<<<NW, 256, 0, stream>>>(hW, as2, ad2, hs, hd, N_NODES);
    attn_agg<<<NW, 256, 0, stream>>>(hW, hs, hd, row_ptr, csr_src, b2, hA, N_NODES, 1);
    // ---- layer 3 (no relu) ----
    gemm_bf16x3<<<GB, 256, 0, stream>>>(hA, wt3h, wt3l, hW, H);
    scores_k<<<NW, 256, 0, stream>>>(hW, as3, ad3, hs, hd, N_NODES);
    attn_agg<<<NW, 256, 0, stream>>>(hW, hs, hd, row_ptr, csr_src, b3, hA, N_NODES, 0);

    // ---- head ----
    pool_k<<<NG, H, 0, stream>>>(hA, batch, pooled, N_NODES);
    fc1_bn_relu<<<NG * 4, 256, 0, stream>>>(pooled, fc1W, fc1b, bng, bnb, bnrm, bnrv, z);
    fc2_sig<<<NG, 320, 0, stream>>>(z, fc2W, fc2b, (float*)d_out);
}